// Round 6
// baseline (32.488 us; speedup 1.0000x reference)
//
#include <hip/hip_runtime.h>
#include <math.h>

// Geometry fixed by reference: B=4, C=3, D=H=W=64.
#define VOXB 262144              // 64^3
#define NVOX 1048576             // 4 * VOXB
#define NACC 14
#define PITCH 65                 // LDS pitch for transposed tile (conflict-free)
#define NBLK 512                 // kernel B grid: 2 blocks per (b,d) plane

// ---------------------------------------------------------------------------
// Squared distance (float) from position i to nearest set bit of 64b mask.
// Empty mask -> 1e6 (acts as inf; clamped to 65535 on pack). A clamped inf
// never beats a genuine candidate: genuine 3D dist^2 <= 3*63^2 = 11907, and
// batches with an empty/full feature take the gsum branch in final assembly.
// ---------------------------------------------------------------------------
__device__ __forceinline__ float n2side(unsigned long long m, int i) {
    unsigned long long right = m >> i;
    unsigned long long left  = m << (63 - i);
    int dr = right ? __builtin_ctzll(right) : 1000;
    int dl = left  ? __builtin_clzll(left)  : 1000;
    int d  = dr < dl ? dr : dl;
    return (float)(d * d);
}

// ---------------------------------------------------------------------------
// Kernel A: build 64-bit d-column masks. Block = (b,h) slab; wave wv owns
// d in [wv*8, wv*8+8); lane = w. Output Mask[b*4096 + h*64 + w] (128 KB).
// ---------------------------------------------------------------------------
__global__ __launch_bounds__(512) void build_masks(
        const int* __restrict__ targets, unsigned long long* __restrict__ Mask) {
    __shared__ unsigned long long Mp[8][64];
    int slab = blockIdx.x;               // b*64 + h
    int b = slab >> 6, h = slab & 63;
    int wv = threadIdx.x >> 6, lane = threadIdx.x & 63;
    int base = b * VOXB + h * 64 + lane;
    unsigned long long bits = 0;
#pragma unroll
    for (int rt = 0; rt < 8; ++rt) {
        int d = wv * 8 + rt;
        int tv = targets[base + d * 4096];
        bits |= ((unsigned long long)(tv == 1)) << d;
    }
    Mp[wv][lane] = bits;
    __syncthreads();
    if (wv == 0) {
        unsigned long long m = Mp[0][lane] | Mp[1][lane] | Mp[2][lane] |
                               Mp[3][lane] | Mp[4][lane] | Mp[5][lane] |
                               Mp[6][lane] | Mp[7][lane];
        Mask[slab * 64 + lane] = m;
    }
}

// ---------------------------------------------------------------------------
// Per-voxel pointwise math + accumulation.
// ---------------------------------------------------------------------------
__device__ __forceinline__ void vox_accum(float l0, float l1, float l2,
                                          int t, int s, float sd, float* acc) {
    float m  = fmaxf(l0, fmaxf(l1, l2));
    float e0 = __expf(l0 - m), e1 = __expf(l1 - m), e2 = __expf(l2 - m);
    float sum = e0 + e1 + e2;
    float inv = 1.0f / sum;
    float p0 = e0 * inv, p1 = e1 * inv, p2 = e2 * inv;
    float logs = __logf(sum);
    float pt, lpt, alpha;
    if (t == 0)      { pt = p0; lpt = l0 - m - logs; alpha = 0.3f; }
    else if (t == 1) { pt = p1; lpt = l1 - m - logs; alpha = 3.0f; }
    else             { pt = p2; lpt = l2 - m - logs; alpha = 0.3f; }
    float om = 1.0f - pt;
    acc[0] += alpha * om * om * lpt;
    acc[1] += (t == 0) ? p0 : 0.f;
    acc[2] += (t == 1) ? p1 : 0.f;
    acc[3] += (t == 2) ? p2 : 0.f;
    acc[4] += p0; acc[5] += p1; acc[6] += p2;
    acc[7] += (t == 0) ? 1.f : 0.f;
    acc[8] += (t == 1) ? 1.f : 0.f;
    acc[9] += (t == 2) ? 1.f : 0.f;
    float fs = (float)s;
    acc[10] += p1 * fs;
    acc[11] += fs;
    acc[12] += p1;
    acc[13] += p1 * sd;
}

// ---------------------------------------------------------------------------
// Kernel B: 2 blocks per (b,d0) plane [h][w]. Loads batch mask set (32 KB)
// into LDS; D-pass via bit-scan (O(1)/voxel); W-pass spiral (all 64 rows,
// 8/wave, row-major LDS, conflict-free); H-pass spiral on transposed tile
// (own half, 4 rows/wave); fused pointwise (contiguous t/s/logits reads) +
// block partials. No fences/atomics.
// ---------------------------------------------------------------------------
__global__ __launch_bounds__(512) void edt_reduce(
        const float* __restrict__ logits, const int* __restrict__ targets,
        const int* __restrict__ skel, const unsigned long long* __restrict__ Mask,
        float* __restrict__ partials) {
    __shared__ unsigned long long Msk[4096];   // 32 KB  [h*64+w]
    __shared__ unsigned int V0[64 * 64];       // 16 KB  [h*64+w]  pos|neg<<16
    __shared__ unsigned int T[64 * PITCH];     // 16.6KB [w*PITCH+h]
    __shared__ float red[8][NACC];
    int plane = blockIdx.x >> 1;               // b*64 + d0
    int half  = blockIdx.x & 1;
    int b = plane >> 6, d0 = plane & 63;
    int t = threadIdx.x;
    int wv = t >> 6, lane = t & 63;            // lane = w
    int hbase = half * 32 + wv * 4;

    // Issue global loads for this block's output rows early (overlap spirals).
    int pbase = b * VOXB + d0 * 4096;          // + h*64 + w
    int   tv[4], sv[4];
    float l0[4], l1[4], l2[4];
    size_t lbase = (size_t)b * (3 * VOXB) + d0 * 4096;
#pragma unroll
    for (int rt = 0; rt < 4; ++rt) {
        int off = pbase + (hbase + rt) * 64 + lane;
        tv[rt] = targets[off];
        sv[rt] = skel[off];
        size_t lb = lbase + (hbase + rt) * 64 + lane;
        l0[rt] = logits[lb];
        l1[rt] = logits[lb + VOXB];
        l2[rt] = logits[lb + 2 * VOXB];
    }

    // Load batch mask set (32 KB contiguous).
#pragma unroll
    for (int k = 0; k < 8; ++k)
        Msk[k * 512 + t] = Mask[b * 4096 + k * 512 + t];
    __syncthreads();

    // D-pass: bit-scan per voxel, all 64 rows (8 rows/wave).
#pragma unroll
    for (int rt = 0; rt < 8; ++rt) {
        int h = wv * 8 + rt;
        unsigned long long m = Msk[h * 64 + lane];
        unsigned int p = (unsigned int)fminf(n2side(m, d0), 65535.f);
        unsigned int n = (unsigned int)fminf(n2side(~m, d0), 65535.f);
        V0[h * 64 + lane] = p | (n << 16);
    }
    __syncthreads();

    // W-pass spiral: all 64 rows (8/wave), result into transposed T.
    {
        float mp[8], mn[8];
#pragma unroll
        for (int rt = 0; rt < 8; ++rt) {
            unsigned int v = V0[(wv * 8 + rt) * 64 + lane];
            mp[rt] = (float)(v & 0xffffu);
            mn[rt] = (float)(v >> 16);
        }
        for (int r = 1; r < 64; ++r) {
            float rr = (float)(r * r);
            int jl = lane - r; jl = jl < 0 ? 0 : jl;
            int jr = lane + r; jr = jr > 63 ? 63 : jr;
            unsigned int vl[8], vr[8];
#pragma unroll
            for (int rt = 0; rt < 8; ++rt) {
                vl[rt] = V0[(wv * 8 + rt) * 64 + jl];
                vr[rt] = V0[(wv * 8 + rt) * 64 + jr];
            }
            bool ok = true;
            float thr = (float)((r + 1) * (r + 1));
#pragma unroll
            for (int rt = 0; rt < 8; ++rt) {
                mp[rt] = fminf(mp[rt], fminf((float)(vl[rt] & 0xffffu),
                                             (float)(vr[rt] & 0xffffu)) + rr);
                mn[rt] = fminf(mn[rt], fminf((float)(vl[rt] >> 16),
                                             (float)(vr[rt] >> 16)) + rr);
                ok = ok && (mp[rt] <= thr) && (mn[rt] <= thr);
            }
            if (__all(ok)) break;            // remaining candidates >= (r+1)^2
        }
#pragma unroll
        for (int rt = 0; rt < 8; ++rt) {
            unsigned int p = (unsigned int)fminf(mp[rt], 65535.f);
            unsigned int n = (unsigned int)fminf(mn[rt], 65535.f);
            T[lane * PITCH + wv * 8 + rt] = p | (n << 16);
        }
    }
    __syncthreads();

    // H-pass spiral on own half (4 rows/wave), then pointwise + accumulate.
    float acc[NACC];
#pragma unroll
    for (int k = 0; k < NACC; ++k) acc[k] = 0.f;
    {
        float mp[4], mn[4];
#pragma unroll
        for (int rt = 0; rt < 4; ++rt) {
            unsigned int v = T[lane * PITCH + hbase + rt];
            mp[rt] = (float)(v & 0xffffu);
            mn[rt] = (float)(v >> 16);
        }
        for (int r = 1; r < 64; ++r) {
            float rr = (float)(r * r);
            unsigned int vl[4], vr[4];
#pragma unroll
            for (int rt = 0; rt < 4; ++rt) {
                int h = hbase + rt;
                int jl = h - r; jl = jl < 0 ? 0 : jl;
                int jr = h + r; jr = jr > 63 ? 63 : jr;
                vl[rt] = T[lane * PITCH + jl];
                vr[rt] = T[lane * PITCH + jr];
            }
            bool ok = true;
            float thr = (float)((r + 1) * (r + 1));
#pragma unroll
            for (int rt = 0; rt < 4; ++rt) {
                mp[rt] = fminf(mp[rt], fminf((float)(vl[rt] & 0xffffu),
                                             (float)(vr[rt] & 0xffffu)) + rr);
                mn[rt] = fminf(mn[rt], fminf((float)(vl[rt] >> 16),
                                             (float)(vr[rt] >> 16)) + rr);
                ok = ok && (mp[rt] <= thr) && (mn[rt] <= thr);
            }
            if (__all(ok)) break;
        }
#pragma unroll
        for (int rt = 0; rt < 4; ++rt) {
            float sd = sqrtf(mp[rt]) - sqrtf(mn[rt]);
            vox_accum(l0[rt], l1[rt], l2[rt], tv[rt], sv[rt], sd, acc);
        }
    }

    // Wave reduce -> LDS -> block partials.
#pragma unroll
    for (int k = 0; k < NACC; ++k) {
        float v = acc[k];
#pragma unroll
        for (int off = 32; off; off >>= 1) v += __shfl_down(v, off, 64);
        if (lane == 0) red[wv][k] = v;
    }
    __syncthreads();
    if (t < NACC) {
        float v = 0.f;
#pragma unroll
        for (int q = 0; q < 8; ++q) v += red[q][t];
        partials[t * NBLK + blockIdx.x] = v;
    }
}

// ---------------------------------------------------------------------------
// Kernel C: final reduction (1 block, 256 threads). Batch b owns blocks
// [b*128, b*128+128); wave w reduces batch w. Thread 0 assembles in f64.
// ---------------------------------------------------------------------------
__global__ __launch_bounds__(256) void final_reduce(
        const float* __restrict__ partials, float* __restrict__ out) {
    __shared__ float sb[NACC][4];
    int w = threadIdx.x >> 6, lane = threadIdx.x & 63;
#pragma unroll
    for (int k = 0; k < NACC; ++k) {
        const float* p = partials + k * NBLK + w * 128;
        float v = p[lane] + p[lane + 64];
#pragma unroll
        for (int off = 32; off; off >>= 1) v += __shfl_down(v, off, 64);
        if (lane == 0) sb[k][w] = v;
    }
    __syncthreads();
    if (threadIdx.x == 0) {
        double S[NACC];
#pragma unroll
        for (int k = 0; k < NACC; ++k)
            S[k] = (double)sb[k][0] + sb[k][1] + sb[k][2] + sb[k][3];
        const double W[3] = {0.3, 3.0, 0.3};
        double focal = -S[0] / (double)NVOX;
        double dice = 0.0;
        for (int c = 0; c < 3; ++c)
            dice += W[c] * (1.0 - (2.0 * S[1 + c] + 1.0) /
                                  (S[4 + c] + S[7 + c] + 1.0));
        double lfd = focal + dice / 3.6;
        double lsk = 1.0 - (S[10] + 1.0) / (S[11] + 1.0);
        double lb = 0.0;
        for (int bb = 0; bb < 4; ++bb) {
            double gs = sb[8][bb];
            double ps = sb[12][bb];
            double tm = sb[13][bb];
            double per;
            if (gs == 0.0)               per = ps / (double)VOXB;
            else if (gs == (double)VOXB) per = 1.0 - ps / (double)VOXB;
            else                         per = tm / (double)VOXB;
            lb += per;
        }
        lb *= 0.25;
        double total = 0.3 * lfd + 0.3 * lsk + 0.2 * lb;
        out[0] = (float)total;
        out[1] = (float)lfd;
        out[2] = (float)lsk;
        out[3] = (float)lb;
    }
}

// ---------------------------------------------------------------------------
extern "C" void kernel_launch(void* const* d_in, const int* in_sizes, int n_in,
                              void* d_out, int out_size, void* d_ws, size_t ws_size,
                              hipStream_t stream) {
    const float* logits  = (const float*)d_in[0];
    const int*   targets = (const int*)d_in[1];
    const int*   skel    = (const int*)d_in[2];
    unsigned long long* Mask = (unsigned long long*)d_ws;   // 16384 u64 (128 KB)
    float* partials = (float*)(Mask + 16384);               // NACC*NBLK floats
    float* out = (float*)d_out;

    build_masks<<<256, 512, 0, stream>>>(targets, Mask);
    edt_reduce<<<NBLK, 512, 0, stream>>>(logits, targets, skel, Mask, partials);
    final_reduce<<<1, 256, 0, stream>>>(partials, out);
}

// Round 7
// 24.834 us; speedup vs baseline: 1.3082x; 1.3082x over previous
//
#include <hip/hip_runtime.h>
#include <math.h>

// Geometry fixed by reference: B=4, C=3, D=H=W=64.
#define VOXB 262144              // 64^3
#define NVOX 1048576             // 4 * VOXB
#define NACC 11
#define PITCH 65                 // transposed-tile pitch: bank=(lane+j)%32, 2-way = free
#define NBLKB 256                // kernel B grid: 1 block per (b,d0) plane
#define CLAMP14 16383            // genuine 3D d^2 <= 3*63^2 = 11907 < 16383; packed
                                 // adds stay < 16383+4096 < 65536 (no u16 overflow)

// ---------------------------------------------------------------------------
// Packed u16 pair ops (VOP3P). pos distance^2 in lo16, neg in hi16.
// ---------------------------------------------------------------------------
__device__ __forceinline__ unsigned pk_min(unsigned a, unsigned b) {
    unsigned d; asm("v_pk_min_u16 %0, %1, %2" : "=v"(d) : "v"(a), "v"(b)); return d;
}
__device__ __forceinline__ unsigned pk_max(unsigned a, unsigned b) {
    unsigned d; asm("v_pk_max_u16 %0, %1, %2" : "=v"(d) : "v"(a), "v"(b)); return d;
}
__device__ __forceinline__ unsigned pk_add(unsigned a, unsigned b) {
    unsigned d; asm("v_pk_add_u16 %0, %1, %2" : "=v"(d) : "v"(a), "v"(b)); return d;
}

// Squared distance (int) from position i to nearest set bit of 64b mask.
// Empty mask -> 1000^2 -> clamped to 16383 ("inf"; never beats a genuine
// candidate; all-empty/all-full volumes take the gsum branch in assembly).
__device__ __forceinline__ unsigned n2i(unsigned long long m, int i) {
    unsigned long long right = m >> i;
    unsigned long long left  = m << (63 - i);
    int dr = right ? __builtin_ctzll(right) : 1000;
    int dl = left  ? __builtin_clzll(left)  : 1000;
    int d  = dr < dl ? dr : dl;
    int d2 = d * d;
    return (unsigned)(d2 > CLAMP14 ? CLAMP14 : d2);
}

// ---------------------------------------------------------------------------
// Kernel A: build 64-bit d-column masks. Block = (b,h) slab; wave wv owns
// d in [wv*8, wv*8+8); lane = w. Output Mask[b*4096 + h*64 + w] (128 KB).
// ---------------------------------------------------------------------------
__global__ __launch_bounds__(512) void build_masks(
        const int* __restrict__ targets, unsigned long long* __restrict__ Mask) {
    __shared__ unsigned long long Mp[8][64];
    int slab = blockIdx.x;               // b*64 + h
    int b = slab >> 6, h = slab & 63;
    int wv = threadIdx.x >> 6, lane = threadIdx.x & 63;
    int base = b * VOXB + h * 64 + lane;
    unsigned long long bits = 0;
#pragma unroll
    for (int rt = 0; rt < 8; ++rt) {
        int d = wv * 8 + rt;
        int tv = targets[base + d * 4096];
        bits |= ((unsigned long long)(tv == 1)) << d;
    }
    Mp[wv][lane] = bits;
    __syncthreads();
    if (wv == 0) {
        unsigned long long m = Mp[0][lane] | Mp[1][lane] | Mp[2][lane] |
                               Mp[3][lane] | Mp[4][lane] | Mp[5][lane] |
                               Mp[6][lane] | Mp[7][lane];
        Mask[slab * 64 + lane] = m;
    }
}

// ---------------------------------------------------------------------------
// Per-voxel pointwise math. 11 accumulators:
// 0 focal, 1..3 inter_c, 4 psum1, 5 psum2, 6 tsum1, 7 tsum2,
// 8 sknum, 9 skden, 10 term(p1*sd).   (psum0/tsum0/predsum derived in C.)
// ---------------------------------------------------------------------------
__device__ __forceinline__ void vox_accum(float l0, float l1, float l2,
                                          int tg, int s, float sd, float* acc) {
    float m  = fmaxf(l0, fmaxf(l1, l2));
    float e0 = __expf(l0 - m), e1 = __expf(l1 - m), e2 = __expf(l2 - m);
    float sum = e0 + e1 + e2;
    float inv = 1.0f / sum;
    float p0 = e0 * inv, p1 = e1 * inv, p2 = e2 * inv;
    float logs = __logf(sum);
    float pt, lpt, alpha;
    if (tg == 0)      { pt = p0; lpt = l0 - m - logs; alpha = 0.3f; }
    else if (tg == 1) { pt = p1; lpt = l1 - m - logs; alpha = 3.0f; }
    else              { pt = p2; lpt = l2 - m - logs; alpha = 0.3f; }
    float om = 1.0f - pt;
    acc[0] += alpha * om * om * lpt;
    acc[1] += (tg == 0) ? p0 : 0.f;
    acc[2] += (tg == 1) ? p1 : 0.f;
    acc[3] += (tg == 2) ? p2 : 0.f;
    acc[4] += p1; acc[5] += p2;
    acc[6] += (tg == 1) ? 1.f : 0.f;
    acc[7] += (tg == 2) ? 1.f : 0.f;
    float fs = (float)s;
    acc[8] += p1 * fs;
    acc[9] += fs;
    acc[10] += p1 * sd;
}

// ---------------------------------------------------------------------------
// Kernel B: ONE 1024-thread block per (b,d0) plane [h][w]; wave wv owns rows
// h in [wv*4, wv*4+4), lane = w. Phases: batch masks -> LDS (32 KB);
// D-pass bit-scan (results stay in registers = W-pass init); W-pass packed
// spiral (wave-local LDS, no barrier); transpose; H-pass packed spiral;
// fused pointwise (prefetched globals); LDS-transpose reduction.
// ---------------------------------------------------------------------------
__global__ __launch_bounds__(1024) void edt_reduce(
        const float* __restrict__ logits, const int* __restrict__ targets,
        const int* __restrict__ skel, const unsigned long long* __restrict__ Mask,
        float* __restrict__ partials) {
    __shared__ union {
        struct {
            unsigned long long Msk[4096];   // 32 KB  [h*64+w]
            unsigned int V0[4096];          // 16 KB  [h*64+w] packed pos|neg<<16
            unsigned int T[64 * PITCH];     // 16.6KB [w*PITCH+h]
        } a;
        float red[NACC * 1024];             // 44 KB, overlaps Msk+V0 only
    } S;
    int plane = blockIdx.x;                 // b*64 + d0
    int b = plane >> 6, d0 = plane & 63;
    int t = threadIdx.x;
    int wv = t >> 6, lane = t & 63;         // lane = w
    int hbase = wv * 4;

    // Prefetch this thread's pointwise inputs (used last; overlap everything).
    int pbase = b * VOXB + d0 * 4096;       // + h*64 + w
    int   tv[4], sv[4];
    float l0[4], l1[4], l2[4];
    size_t lbase = (size_t)b * (3 * VOXB) + d0 * 4096;
#pragma unroll
    for (int rt = 0; rt < 4; ++rt) {
        int off = pbase + (hbase + rt) * 64 + lane;
        tv[rt] = targets[off];
        sv[rt] = skel[off];
        size_t lb = lbase + (hbase + rt) * 64 + lane;
        l0[rt] = logits[lb];
        l1[rt] = logits[lb + VOXB];
        l2[rt] = logits[lb + 2 * VOXB];
    }

    // Load batch mask set (32 KB contiguous, 4 u64 per thread).
#pragma unroll
    for (int k = 0; k < 4; ++k)
        S.a.Msk[k * 1024 + t] = Mask[b * 4096 + k * 1024 + t];
    __syncthreads();

    // D-pass (bit-scan) for own rows; keep packed result as W-pass init.
    unsigned mp[4];
#pragma unroll
    for (int rt = 0; rt < 4; ++rt) {
        unsigned long long m = S.a.Msk[(hbase + rt) * 64 + lane];
        unsigned v = n2i(m, d0) | (n2i(~m, d0) << 16);
        S.a.V0[(hbase + rt) * 64 + lane] = v;
        mp[rt] = v;
    }
    // W-pass packed spiral (reads only this wave's rows -> wave-local, no barrier).
    for (int r = 1; r < 64; ++r) {
        int jl = lane - r; jl = jl < 0 ? 0 : jl;
        int jr = lane + r; jr = jr > 63 ? 63 : jr;
        unsigned rr2 = (unsigned)(r * r) * 0x10001u;
        unsigned mx = 0;
#pragma unroll
        for (int rt = 0; rt < 4; ++rt) {
            unsigned a = S.a.V0[(hbase + rt) * 64 + jl];
            unsigned c = S.a.V0[(hbase + rt) * 64 + jr];
            mp[rt] = pk_min(mp[rt], pk_add(pk_min(a, c), rr2));
            mx = pk_max(mx, mp[rt]);
        }
        unsigned thr = (unsigned)((r + 1) * (r + 1));
        bool ok = ((mx & 0xffffu) <= thr) && ((mx >> 16) <= thr);
        if (__all(ok)) break;               // remaining candidates >= (r+1)^2
    }
#pragma unroll
    for (int rt = 0; rt < 4; ++rt)          // re-clamp to 14b, store transposed
        S.a.T[lane * PITCH + hbase + rt] = pk_min(mp[rt], 0x3FFF3FFFu);
    __syncthreads();

    // H-pass packed spiral on transposed tile.
    unsigned mh[4];
#pragma unroll
    for (int rt = 0; rt < 4; ++rt) mh[rt] = S.a.T[lane * PITCH + hbase + rt];
    for (int r = 1; r < 64; ++r) {
        unsigned rr2 = (unsigned)(r * r) * 0x10001u;
        unsigned mx = 0;
#pragma unroll
        for (int rt = 0; rt < 4; ++rt) {
            int h = hbase + rt;
            int jl = h - r; jl = jl < 0 ? 0 : jl;
            int jr = h + r; jr = jr > 63 ? 63 : jr;
            unsigned a = S.a.T[lane * PITCH + jl];
            unsigned c = S.a.T[lane * PITCH + jr];
            mh[rt] = pk_min(mh[rt], pk_add(pk_min(a, c), rr2));
            mx = pk_max(mx, mh[rt]);
        }
        unsigned thr = (unsigned)((r + 1) * (r + 1));
        bool ok = ((mx & 0xffffu) <= thr) && ((mx >> 16) <= thr);
        if (__all(ok)) break;
    }

    // Pointwise + per-thread accumulation (prefetched inputs arrive here).
    float acc[NACC];
#pragma unroll
    for (int k = 0; k < NACC; ++k) acc[k] = 0.f;
#pragma unroll
    for (int rt = 0; rt < 4; ++rt) {
        float sd = sqrtf((float)(mh[rt] & 0xffffu)) - sqrtf((float)(mh[rt] >> 16));
        vox_accum(l0[rt], l1[rt], l2[rt], tv[rt], sv[rt], sd, acc);
    }

    // LDS-transpose reduction: red[k][t] (overlaps dead Msk+V0, not T).
    __syncthreads();                        // all H-pass T reads done
#pragma unroll
    for (int k = 0; k < NACC; ++k) S.red[k * 1024 + t] = acc[k];
    __syncthreads();
    if (wv < NACC) {                        // wave wv reduces value wv
        const float* p = S.red + wv * 1024;
        float v = 0.f;
#pragma unroll
        for (int c = 0; c < 16; ++c) v += p[lane + c * 64];
#pragma unroll
        for (int off = 32; off; off >>= 1) v += __shfl_down(v, off, 64);
        if (lane == 0) partials[wv * NBLKB + blockIdx.x] = v;
    }
}

// ---------------------------------------------------------------------------
// Kernel C: final reduction (1 block, 256 threads). Batch b owns blocks
// [b*64, b*64+64); wave w reduces batch w. Thread 0 assembles in f64.
// ---------------------------------------------------------------------------
__global__ __launch_bounds__(256) void final_reduce(
        const float* __restrict__ partials, float* __restrict__ out) {
    __shared__ float sb[NACC][4];
    int w = threadIdx.x >> 6, lane = threadIdx.x & 63;
#pragma unroll
    for (int k = 0; k < NACC; ++k) {
        float v = partials[k * NBLKB + w * 64 + lane];
#pragma unroll
        for (int off = 32; off; off >>= 1) v += __shfl_down(v, off, 64);
        if (lane == 0) sb[k][w] = v;
    }
    __syncthreads();
    if (threadIdx.x == 0) {
        double S[NACC];
#pragma unroll
        for (int k = 0; k < NACC; ++k)
            S[k] = (double)sb[k][0] + sb[k][1] + sb[k][2] + sb[k][3];
        double psum0 = (double)NVOX - S[4] - S[5];
        double tsum0 = (double)NVOX - S[6] - S[7];   // exact (integer counts)
        double focal = -S[0] / (double)NVOX;
        double dice =
            0.3 * (1.0 - (2.0 * S[1] + 1.0) / (psum0 + tsum0 + 1.0)) +
            3.0 * (1.0 - (2.0 * S[2] + 1.0) / (S[4] + S[6] + 1.0)) +
            0.3 * (1.0 - (2.0 * S[3] + 1.0) / (S[5] + S[7] + 1.0));
        double lfd = focal + dice / 3.6;
        double lsk = 1.0 - (S[8] + 1.0) / (S[9] + 1.0);
        double lb = 0.0;
        for (int bb = 0; bb < 4; ++bb) {
            double gs = sb[6][bb];          // per-batch count of targets==1
            double ps = sb[4][bb];          // per-batch sum of p1
            double tm = sb[10][bb];         // per-batch sum of p1*sd
            double per;
            if (gs == 0.0)               per = ps / (double)VOXB;
            else if (gs == (double)VOXB) per = 1.0 - ps / (double)VOXB;
            else                         per = tm / (double)VOXB;
            lb += per;
        }
        lb *= 0.25;
        double total = 0.3 * lfd + 0.3 * lsk + 0.2 * lb;
        out[0] = (float)total;
        out[1] = (float)lfd;
        out[2] = (float)lsk;
        out[3] = (float)lb;
    }
}

// ---------------------------------------------------------------------------
extern "C" void kernel_launch(void* const* d_in, const int* in_sizes, int n_in,
                              void* d_out, int out_size, void* d_ws, size_t ws_size,
                              hipStream_t stream) {
    const float* logits  = (const float*)d_in[0];
    const int*   targets = (const int*)d_in[1];
    const int*   skel    = (const int*)d_in[2];
    unsigned long long* Mask = (unsigned long long*)d_ws;   // 16384 u64 (128 KB)
    float* partials = (float*)(Mask + 16384);               // NACC*NBLKB floats
    float* out = (float*)d_out;

    build_masks<<<256, 512, 0, stream>>>(targets, Mask);
    edt_reduce<<<NBLKB, 1024, 0, stream>>>(logits, targets, skel, Mask, partials);
    final_reduce<<<1, 256, 0, stream>>>(partials, out);
}

// Round 8
// 24.484 us; speedup vs baseline: 1.3269x; 1.0143x over previous
//
#include <hip/hip_runtime.h>
#include <math.h>

// Geometry fixed by reference: B=4, C=3, D=H=W=64.
#define VOXB 262144              // 64^3
#define NVOX 1048576             // 4 * VOXB
#define NACC 11
#define PITCH 68                 // u32 pitch: mult-of-4 => aligned b128; %32=4 => even banks
#define NBLKB 256                // kernel B grid: 1 block per (b,d0) plane
#define CLAMP14 16383            // genuine 3D d^2 <= 3*63^2 = 11907 < 16383; packed u16
                                 // adds stay <= 20352+3969 < 65536 (no overflow)

// ---------------------------------------------------------------------------
// Packed u16 pair ops (VOP3P). pos distance^2 in lo16, neg in hi16.
// ---------------------------------------------------------------------------
__device__ __forceinline__ unsigned pk_min(unsigned a, unsigned b) {
    unsigned d; asm("v_pk_min_u16 %0, %1, %2" : "=v"(d) : "v"(a), "v"(b)); return d;
}
__device__ __forceinline__ unsigned pk_max(unsigned a, unsigned b) {
    unsigned d; asm("v_pk_max_u16 %0, %1, %2" : "=v"(d) : "v"(a), "v"(b)); return d;
}
__device__ __forceinline__ unsigned pk_add(unsigned a, unsigned b) {
    unsigned d; asm("v_pk_add_u16 %0, %1, %2" : "=v"(d) : "v"(a), "v"(b)); return d;
}

// Squared distance (int) from position i to nearest set bit of 64b mask.
// Empty mask -> clamped 16383 ("inf"; never beats a genuine candidate;
// all-empty/all-full volumes take the gsum branch in final assembly).
__device__ __forceinline__ unsigned n2i(unsigned long long m, int i) {
    unsigned long long right = m >> i;
    unsigned long long left  = m << (63 - i);
    int dr = right ? __builtin_ctzll(right) : 1000;
    int dl = left  ? __builtin_clzll(left)  : 1000;
    int d  = dr < dl ? dr : dl;
    int d2 = d * d;
    return (unsigned)(d2 > CLAMP14 ? CLAMP14 : d2);
}

// lgkm-only barrier: LDS ordering without draining outstanding global loads
// (keeps prefetched vector loads in flight across the spiral phases).
__device__ __forceinline__ void lgkm_barrier() {
    asm volatile("s_waitcnt lgkmcnt(0)" ::: "memory");
    __builtin_amdgcn_s_barrier();
    asm volatile("" ::: "memory");
}

// ---------------------------------------------------------------------------
// Kernel A: build 64-bit d-column masks. Block = (b,h) slab; wave wv owns
// d in [wv*8, wv*8+8); lane = w. Output Mask[b*4096 + h*64 + w] (128 KB).
// ---------------------------------------------------------------------------
__global__ __launch_bounds__(512) void build_masks(
        const int* __restrict__ targets, unsigned long long* __restrict__ Mask) {
    __shared__ unsigned long long Mp[8][64];
    int slab = blockIdx.x;               // b*64 + h
    int b = slab >> 6, h = slab & 63;
    int wv = threadIdx.x >> 6, lane = threadIdx.x & 63;
    int base = b * VOXB + h * 64 + lane;
    unsigned long long bits = 0;
#pragma unroll
    for (int rt = 0; rt < 8; ++rt) {
        int d = wv * 8 + rt;
        int tv = targets[base + d * 4096];
        bits |= ((unsigned long long)(tv == 1)) << d;
    }
    Mp[wv][lane] = bits;
    __syncthreads();
    if (wv == 0) {
        unsigned long long m = Mp[0][lane] | Mp[1][lane] | Mp[2][lane] |
                               Mp[3][lane] | Mp[4][lane] | Mp[5][lane] |
                               Mp[6][lane] | Mp[7][lane];
        Mask[slab * 64 + lane] = m;
    }
}

// ---------------------------------------------------------------------------
// Per-voxel pointwise math. 11 accumulators:
// 0 focal, 1..3 inter_c, 4 psum1, 5 psum2, 6 tsum1, 7 tsum2,
// 8 sknum, 9 skden, 10 term(p1*sd).   (psum0/tsum0/predsum derived in C.)
// ---------------------------------------------------------------------------
__device__ __forceinline__ void vox_accum(float l0, float l1, float l2,
                                          int tg, int s, float sd, float* acc) {
    float m  = fmaxf(l0, fmaxf(l1, l2));
    float e0 = __expf(l0 - m), e1 = __expf(l1 - m), e2 = __expf(l2 - m);
    float sum = e0 + e1 + e2;
    float inv = 1.0f / sum;
    float p0 = e0 * inv, p1 = e1 * inv, p2 = e2 * inv;
    float logs = __logf(sum);
    float pt, lpt, alpha;
    if (tg == 0)      { pt = p0; lpt = l0 - m - logs; alpha = 0.3f; }
    else if (tg == 1) { pt = p1; lpt = l1 - m - logs; alpha = 3.0f; }
    else              { pt = p2; lpt = l2 - m - logs; alpha = 0.3f; }
    float om = 1.0f - pt;
    acc[0] += alpha * om * om * lpt;
    acc[1] += (tg == 0) ? p0 : 0.f;
    acc[2] += (tg == 1) ? p1 : 0.f;
    acc[3] += (tg == 2) ? p2 : 0.f;
    acc[4] += p1; acc[5] += p2;
    acc[6] += (tg == 1) ? 1.f : 0.f;
    acc[7] += (tg == 2) ? 1.f : 0.f;
    float fs = (float)s;
    acc[8] += p1 * fs;
    acc[9] += fs;
    acc[10] += p1 * sd;
}

// ---------------------------------------------------------------------------
// Kernel B: one 1024-thread block per (b,d0) plane. Ownership for D/W passes:
// thread (wv,lane) owns voxels (h=wv*4+rt, w=lane). Ownership for H pass +
// pointwise: (h=lane, w=wv*4+rt) -- re-partitioned so BOTH spirals read
// 2 x ds_read_b128 per iteration and pointwise loads are dwordx4.
// Only 2 lgkm-only barriers; global prefetch stays in flight throughout.
// ---------------------------------------------------------------------------
__global__ __launch_bounds__(1024) void edt_reduce(
        const float* __restrict__ logits, const int* __restrict__ targets,
        const int* __restrict__ skel, const unsigned long long* __restrict__ Mask,
        float* __restrict__ partials) {
    __shared__ unsigned V0T[64 * PITCH];   // [w][h] packed D-dist (pos|neg<<16)
    __shared__ unsigned T2 [64 * PITCH];   // [h][w] packed W+D dist
    __shared__ float red[NACC * 1024];     // 44 KB
    int plane = blockIdx.x;                // b*64 + d0
    int b = plane >> 6, d0 = plane & 63;
    int t = threadIdx.x;
    int wv = t >> 6, lane = t & 63;
    int hbase = wv * 4, wbase = wv * 4;

    // --- issue all global loads up front (land during the spirals) ---------
    const unsigned long long* mb = Mask + b * 4096;
    unsigned long long mk[4];
#pragma unroll
    for (int rt = 0; rt < 4; ++rt) mk[rt] = mb[(hbase + rt) * 64 + lane];

    int pbase = b * VOXB + d0 * 4096 + lane * 64 + wbase;   // (h=lane, w=wbase)
    int4 tv4 = *reinterpret_cast<const int4*>(targets + pbase);
    int4 sv4 = *reinterpret_cast<const int4*>(skel + pbase);
    size_t lbase = (size_t)b * (3 * VOXB) + d0 * 4096 + lane * 64 + wbase;
    float4 L0 = *reinterpret_cast<const float4*>(logits + lbase);
    float4 L1 = *reinterpret_cast<const float4*>(logits + lbase + VOXB);
    float4 L2 = *reinterpret_cast<const float4*>(logits + lbase + 2 * VOXB);

    // --- D-pass: bit-scan, packed; write V0T[w=lane][hbase..+3] (b128) -----
    unsigned mp[4];
#pragma unroll
    for (int rt = 0; rt < 4; ++rt)
        mp[rt] = n2i(mk[rt], d0) | (n2i(~mk[rt], d0) << 16);
    *reinterpret_cast<uint4*>(&V0T[lane * PITCH + hbase]) =
        make_uint4(mp[0], mp[1], mp[2], mp[3]);

    // --- W-pass spiral (wave-local: rows jl,jr written by this wave) -------
    for (int r = 1; r < 64; ++r) {
        int jl = lane - r; jl = jl < 0 ? 0 : jl;
        int jr = lane + r; jr = jr > 63 ? 63 : jr;
        uint4 qa = *reinterpret_cast<const uint4*>(&V0T[jl * PITCH + hbase]);
        uint4 qc = *reinterpret_cast<const uint4*>(&V0T[jr * PITCH + hbase]);
        unsigned rr2 = (unsigned)(r * r) * 0x10001u;
        unsigned mx;
        mp[0] = pk_min(mp[0], pk_add(pk_min(qa.x, qc.x), rr2)); mx = mp[0];
        mp[1] = pk_min(mp[1], pk_add(pk_min(qa.y, qc.y), rr2)); mx = pk_max(mx, mp[1]);
        mp[2] = pk_min(mp[2], pk_add(pk_min(qa.z, qc.z), rr2)); mx = pk_max(mx, mp[2]);
        mp[3] = pk_min(mp[3], pk_add(pk_min(qa.w, qc.w), rr2)); mx = pk_max(mx, mp[3]);
        unsigned thr = (unsigned)((r + 1) * (r + 1));
        if (__all(((mx & 0xffffu) <= thr) && ((mx >> 16) <= thr))) break;
    }
    // write T2[h=hbase+rt][w=lane] (4 x b32, conflict-free)
#pragma unroll
    for (int rt = 0; rt < 4; ++rt) T2[(hbase + rt) * PITCH + lane] = mp[rt];
    lgkm_barrier();                        // T2 handoff (globals stay in flight)

    // --- H-pass spiral at NEW ownership (h=lane, w=wbase..+3) --------------
    uint4 q0 = *reinterpret_cast<const uint4*>(&T2[lane * PITCH + wbase]);
    unsigned mh[4] = {q0.x, q0.y, q0.z, q0.w};
    for (int r = 1; r < 64; ++r) {
        int jl = lane - r; jl = jl < 0 ? 0 : jl;
        int jr = lane + r; jr = jr > 63 ? 63 : jr;
        uint4 qa = *reinterpret_cast<const uint4*>(&T2[jl * PITCH + wbase]);
        uint4 qc = *reinterpret_cast<const uint4*>(&T2[jr * PITCH + wbase]);
        unsigned rr2 = (unsigned)(r * r) * 0x10001u;
        unsigned mx;
        mh[0] = pk_min(mh[0], pk_add(pk_min(qa.x, qc.x), rr2)); mx = mh[0];
        mh[1] = pk_min(mh[1], pk_add(pk_min(qa.y, qc.y), rr2)); mx = pk_max(mx, mh[1]);
        mh[2] = pk_min(mh[2], pk_add(pk_min(qa.z, qc.z), rr2)); mx = pk_max(mx, mh[2]);
        mh[3] = pk_min(mh[3], pk_add(pk_min(qa.w, qc.w), rr2)); mx = pk_max(mx, mh[3]);
        unsigned thr = (unsigned)((r + 1) * (r + 1));
        if (__all(((mx & 0xffffu) <= thr) && ((mx >> 16) <= thr))) break;
    }

    // --- pointwise (vector loads arrive here) + accumulate ------------------
    float acc[NACC];
#pragma unroll
    for (int k = 0; k < NACC; ++k) acc[k] = 0.f;
    {
        float sd0 = sqrtf((float)(mh[0] & 0xffffu)) - sqrtf((float)(mh[0] >> 16));
        float sd1 = sqrtf((float)(mh[1] & 0xffffu)) - sqrtf((float)(mh[1] >> 16));
        float sd2 = sqrtf((float)(mh[2] & 0xffffu)) - sqrtf((float)(mh[2] >> 16));
        float sd3 = sqrtf((float)(mh[3] & 0xffffu)) - sqrtf((float)(mh[3] >> 16));
        vox_accum(L0.x, L1.x, L2.x, tv4.x, sv4.x, sd0, acc);
        vox_accum(L0.y, L1.y, L2.y, tv4.y, sv4.y, sd1, acc);
        vox_accum(L0.z, L1.z, L2.z, tv4.z, sv4.z, sd2, acc);
        vox_accum(L0.w, L1.w, L2.w, tv4.w, sv4.w, sd3, acc);
    }

    // --- LDS-transpose reduction -> block partials --------------------------
#pragma unroll
    for (int k = 0; k < NACC; ++k) red[k * 1024 + t] = acc[k];
    lgkm_barrier();
    if (wv < NACC) {                       // wave wv reduces accumulator wv
        const float* p = red + wv * 1024;
        float v = 0.f;
#pragma unroll
        for (int c = 0; c < 16; ++c) v += p[lane + c * 64];
#pragma unroll
        for (int off = 32; off; off >>= 1) v += __shfl_down(v, off, 64);
        if (lane == 0) partials[wv * NBLKB + blockIdx.x] = v;
    }
}

// ---------------------------------------------------------------------------
// Kernel C: final reduction (1 block, 256 threads). Batch b owns blocks
// [b*64, b*64+64); wave w reduces batch w. Thread 0 assembles in f64.
// ---------------------------------------------------------------------------
__global__ __launch_bounds__(256) void final_reduce(
        const float* __restrict__ partials, float* __restrict__ out) {
    __shared__ float sb[NACC][4];
    int w = threadIdx.x >> 6, lane = threadIdx.x & 63;
#pragma unroll
    for (int k = 0; k < NACC; ++k) {
        float v = partials[k * NBLKB + w * 64 + lane];
#pragma unroll
        for (int off = 32; off; off >>= 1) v += __shfl_down(v, off, 64);
        if (lane == 0) sb[k][w] = v;
    }
    __syncthreads();
    if (threadIdx.x == 0) {
        double S[NACC];
#pragma unroll
        for (int k = 0; k < NACC; ++k)
            S[k] = (double)sb[k][0] + sb[k][1] + sb[k][2] + sb[k][3];
        double psum0 = (double)NVOX - S[4] - S[5];
        double tsum0 = (double)NVOX - S[6] - S[7];   // exact (integer counts)
        double focal = -S[0] / (double)NVOX;
        double dice =
            0.3 * (1.0 - (2.0 * S[1] + 1.0) / (psum0 + tsum0 + 1.0)) +
            3.0 * (1.0 - (2.0 * S[2] + 1.0) / (S[4] + S[6] + 1.0)) +
            0.3 * (1.0 - (2.0 * S[3] + 1.0) / (S[5] + S[7] + 1.0));
        double lfd = focal + dice / 3.6;
        double lsk = 1.0 - (S[8] + 1.0) / (S[9] + 1.0);
        double lb = 0.0;
        for (int bb = 0; bb < 4; ++bb) {
            double gs = sb[6][bb];          // per-batch count of targets==1
            double ps = sb[4][bb];          // per-batch sum of p1
            double tm = sb[10][bb];         // per-batch sum of p1*sd
            double per;
            if (gs == 0.0)               per = ps / (double)VOXB;
            else if (gs == (double)VOXB) per = 1.0 - ps / (double)VOXB;
            else                         per = tm / (double)VOXB;
            lb += per;
        }
        lb *= 0.25;
        double total = 0.3 * lfd + 0.3 * lsk + 0.2 * lb;
        out[0] = (float)total;
        out[1] = (float)lfd;
        out[2] = (float)lsk;
        out[3] = (float)lb;
    }
}

// ---------------------------------------------------------------------------
extern "C" void kernel_launch(void* const* d_in, const int* in_sizes, int n_in,
                              void* d_out, int out_size, void* d_ws, size_t ws_size,
                              hipStream_t stream) {
    const float* logits  = (const float*)d_in[0];
    const int*   targets = (const int*)d_in[1];
    const int*   skel    = (const int*)d_in[2];
    unsigned long long* Mask = (unsigned long long*)d_ws;   // 16384 u64 (128 KB)
    float* partials = (float*)(Mask + 16384);               // NACC*NBLKB floats
    float* out = (float*)d_out;

    build_masks<<<256, 512, 0, stream>>>(targets, Mask);
    edt_reduce<<<NBLKB, 1024, 0, stream>>>(logits, targets, skel, Mask, partials);
    final_reduce<<<1, 256, 0, stream>>>(partials, out);
}